// Round 1
// baseline (378.532 us; speedup 1.0000x reference)
//
#include <hip/hip_runtime.h>

#define B_   8
#define N_   4096
#define D_   1024
#define HID  128
#define QKVW 384
#define M_   (B_*N_)   // 32768 rows

typedef unsigned short u16;
typedef unsigned int   u32;
typedef __attribute__((ext_vector_type(8))) short bf16x8;
typedef __attribute__((ext_vector_type(4))) float f32x4;

__device__ __forceinline__ u16 f2bf(float f){
  u32 u = __float_as_uint(f);
  u32 r = (u + 0x7fffu + ((u >> 16) & 1u)) >> 16;   // RNE
  return (u16)r;
}

// async global->LDS, 16B per lane; LDS dst = wave-uniform base + lane*16
#define GLOAD_LDS16(g, l) __builtin_amdgcn_global_load_lds( \
    (const __attribute__((address_space(1))) unsigned int*)(g), \
    (__attribute__((address_space(3))) unsigned int*)(l), 16, 0, 0)

// ---------------------------------------------------------------------------
// 0. QKV weights -> bf16, k-contiguous transposed (wout stays fp32; consumed
//    by fold_kernel directly)
// ---------------------------------------------------------------------------
__global__ void convw_kernel(const float* __restrict__ wqkv, u16* __restrict__ wqT){
  int idx = blockIdx.x * 256 + threadIdx.x;
  if (idx < QKVW * D_){
    int n = idx >> 10, k = idx & 1023;
    wqT[idx] = f2bf(wqkv[(size_t)k * QKVW + n]);
  }
}

// ---------------------------------------------------------------------------
// 1. LayerNorm over dim=1024. Wave-per-row, 4 rows/block, NO barriers:
//    64 lanes x 16 floats, 6-step butterfly shfl_xor reduce.
// ---------------------------------------------------------------------------
__global__ __launch_bounds__(256)
void ln_kernel(const float* __restrict__ x, const float* __restrict__ gamma,
               const float* __restrict__ beta, u16* __restrict__ xn){
  const int wid = threadIdx.x >> 6, lane = threadIdx.x & 63;
  const size_t row = (size_t)blockIdx.x * 4 + wid;
  const float4* xr = (const float4*)(x + row * D_);
  float4 v[4];
  float s = 0.f, q = 0.f;
  #pragma unroll
  for (int j = 0; j < 4; j++){
    v[j] = xr[j*64 + lane];
    s += v[j].x + v[j].y + v[j].z + v[j].w;
    q += v[j].x*v[j].x + v[j].y*v[j].y + v[j].z*v[j].z + v[j].w*v[j].w;
  }
  #pragma unroll
  for (int off = 32; off > 0; off >>= 1){
    s += __shfl_xor(s, off, 64);
    q += __shfl_xor(q, off, 64);
  }
  const float mean = s * (1.f / D_);
  const float rstd = rsqrtf(q * (1.f / D_) - mean * mean + 1e-5f);
  uint2* xo = (uint2*)(xn + row * D_);
  #pragma unroll
  for (int j = 0; j < 4; j++){
    const float4 g  = ((const float4*)gamma)[j*64 + lane];
    const float4 be = ((const float4*)beta)[j*64 + lane];
    float y0 = (v[j].x - mean) * rstd * g.x + be.x;
    float y1 = (v[j].y - mean) * rstd * g.y + be.y;
    float y2 = (v[j].z - mean) * rstd * g.z + be.z;
    float y3 = (v[j].w - mean) * rstd * g.w + be.w;
    uint2 o;
    o.x = (u32)f2bf(y0) | ((u32)f2bf(y1) << 16);
    o.y = (u32)f2bf(y2) | ((u32)f2bf(y3) << 16);
    xo[j*64 + lane] = o;
  }
}

// ---------------------------------------------------------------------------
// 2. QKV GEMM: [M x 384] = xn[M x 1024] * wqT[384 x 1024]^T
//    Tile 128x192, grid (2, M/128). 4 waves in 2x2; wave = 64 rows x 96 cols,
//    acc 4x6. BK=32, m97 2-barrier structure, gload_lds width-16 staging.
//    Per wave per K-step: 5 gloads / 10 ds_read_b128 / 24 MFMA (was 7/10/24).
//    Output: cols<128 -> q as bf16 (qb); cols>=128 -> k,v fp32 (kv, 256-wide).
// ---------------------------------------------------------------------------
__global__ __launch_bounds__(256)
void gemm_qkv(const u16* __restrict__ A, const u16* __restrict__ Bt,
              u16* __restrict__ qb, float* __restrict__ kv){
  __shared__ __align__(16) u16 As[128 * 32];   // 8 KB
  __shared__ __align__(16) u16 Bs[192 * 32];   // 12 KB
  const int t = threadIdx.x, lane = t & 63, w = t >> 6;
  const int rowTile = blockIdx.y * 128;
  const int colTile = blockIdx.x * 192;
  // staging: lane covers row lr, phys chunk lane&3, logical chunk lc
  const int lr = lane >> 2;
  const int lc = (lane & 3) ^ ((lane >> 3) & 3);       // phys ^ ((row>>1)&3)
  const u16* pA0 = A  + (size_t)(rowTile + (w*2    )*16 + lr) * 1024 + lc * 8;
  const u16* pA1 = pA0 + 16 * 1024;
  const u16* pB0 = Bt + (size_t)(colTile + (w*3    )*16 + lr) * 1024 + lc * 8;
  const u16* pB1 = pB0 + 16 * 1024;
  const u16* pB2 = pB0 + 32 * 1024;
  u16* dA0 = &As[(w*2    ) * 512];   // 512 u16 = 16 rows x 32
  u16* dA1 = dA0 + 512;
  u16* dB0 = &Bs[(w*3    ) * 512];
  u16* dB1 = dB0 + 512;
  u16* dB2 = dB0 + 1024;
  const int fr = lane & 15, q = lane >> 4;
  const int pc = (q ^ ((fr >> 1) & 3)) * 8;            // phys chunk (halfwords)
  const int wr = (w >> 1) * 64, wc = (w & 1) * 96;

  f32x4 acc[4][6];
  #pragma unroll
  for (int i = 0; i < 4; i++)
    #pragma unroll
    for (int j = 0; j < 6; j++)
      #pragma unroll
      for (int r = 0; r < 4; r++) acc[i][j][r] = 0.f;

  for (int k0 = 0; k0 < 1024; k0 += 32){
    __syncthreads();                  // previous iteration's reads done
    GLOAD_LDS16(pA0, dA0);
    GLOAD_LDS16(pA1, dA1);
    GLOAD_LDS16(pB0, dB0);
    GLOAD_LDS16(pB1, dB1);
    GLOAD_LDS16(pB2, dB2);
    pA0 += 32; pA1 += 32; pB0 += 32; pB1 += 32; pB2 += 32;
    __syncthreads();                  // vmcnt(0) drained before barrier
    bf16x8 af[4], bf[6];
    #pragma unroll
    for (int mi = 0; mi < 4; mi++) af[mi] = *(const bf16x8*)&As[(wr + mi*16 + fr)*32 + pc];
    #pragma unroll
    for (int ni = 0; ni < 6; ni++) bf[ni] = *(const bf16x8*)&Bs[(wc + ni*16 + fr)*32 + pc];
    #pragma unroll
    for (int mi = 0; mi < 4; mi++)
      #pragma unroll
      for (int ni = 0; ni < 6; ni++)
        acc[mi][ni] = __builtin_amdgcn_mfma_f32_16x16x32_bf16(af[mi], bf[ni], acc[mi][ni], 0, 0, 0);
  }

  #pragma unroll
  for (int mi = 0; mi < 4; mi++){
    #pragma unroll
    for (int ni = 0; ni < 6; ni++){
      #pragma unroll
      for (int r = 0; r < 4; r++){
        int row = rowTile + wr + mi*16 + q*4 + r;
        int col = colTile + wc + ni*16 + fr;
        float val = acc[mi][ni][r];
        if (col < HID) qb[(size_t)row * HID + col] = f2bf(val);   // q, bf16
        else           kv[(size_t)row * 256 + (col - HID)] = val; // k,v fp32
      }
    }
  }
}

// ---------------------------------------------------------------------------
// 3. Softmax/context partials per (256-row chunk, head, batch). 512 blocks.
//    kv layout: [row][256] fp32, k = cols 0..127, v = cols 128..255.
// ---------------------------------------------------------------------------
__global__ __launch_bounds__(256)
void ctx_partial(const float* __restrict__ kv, float* __restrict__ pctx,
                 float* __restrict__ psum){
  const int c = blockIdx.x, h = blockIdx.y, b = blockIdx.z;
  const int t = threadIdx.x;
  __shared__ float ek[64][32], vv[64][32];
  const int d = t >> 3, e0 = (t & 7) * 4;
  const int rl = t >> 2, cg = (t & 3) * 8;
  float a0=0.f, a1=0.f, a2=0.f, a3=0.f, ks=0.f;
  const size_t rowbase = (size_t)b * N_ + (size_t)c * 256;
  for (int s = 0; s < 4; ++s){
    __syncthreads();
    const float* src = kv + (rowbase + s*64 + rl) * 256 + h*32 + cg;
    float4 ka = *(const float4*)(src);
    float4 kb = *(const float4*)(src + 4);
    float4 va = *(const float4*)(src + 128);
    float4 vb = *(const float4*)(src + 132);
    float4 ea = make_float4(__expf(ka.x), __expf(ka.y), __expf(ka.z), __expf(ka.w));
    float4 eb = make_float4(__expf(kb.x), __expf(kb.y), __expf(kb.z), __expf(kb.w));
    *(float4*)&ek[rl][cg]     = ea;
    *(float4*)&ek[rl][cg + 4] = eb;
    *(float4*)&vv[rl][cg]     = va;
    *(float4*)&vv[rl][cg + 4] = vb;
    __syncthreads();
    #pragma unroll 8
    for (int n = 0; n < 64; ++n){
      float kd = ek[n][d];
      float4 vn = *(const float4*)&vv[n][e0];
      a0 += kd * vn.x; a1 += kd * vn.y; a2 += kd * vn.z; a3 += kd * vn.w;
      ks += kd;
    }
  }
  float* op = pctx + (((size_t)(b*4 + h) * 16 + c) * 1024) + d*32 + e0;
  *(float4*)op = make_float4(a0, a1, a2, a3);
  if (e0 == 0) psum[((size_t)(b*4 + h) * 16 + c) * 32 + d] = ks;
}

// ---------------------------------------------------------------------------
// 4. Reduce partials -> ctxT[bh][e*32+d] (normalized, q-scale folded)
// ---------------------------------------------------------------------------
__global__ void ctx_reduce(const float* __restrict__ pctx, const float* __restrict__ psum,
                           float* __restrict__ ctxT){
  int bh = blockIdx.x, t = threadIdx.x;   // 1024 threads: t = d*32 + e
  int d = t >> 5, e = t & 31;
  float s = 0.f, S = 0.f;
  for (int c = 0; c < 16; ++c){
    s += pctx[((size_t)bh * 16 + c) * 1024 + t];
    S += psum[((size_t)bh * 16 + c) * 32 + d];
  }
  ctxT[(size_t)bh * 1024 + e*32 + d] = s / S * 0.17677669529663689f; // * 32^-0.5
}

// ---------------------------------------------------------------------------
// 5. Fold context into output weights:
//    FbT[b][c][h*32+d] = sum_e ctxT[b*4+h][e*32+d] * wout[(h*32+e)*1024 + c]
//    (bf16, k-contiguous B operand for the final GEMM). 33M MACs total.
// ---------------------------------------------------------------------------
__global__ __launch_bounds__(256)
void fold_kernel(const float* __restrict__ ctxT, const float* __restrict__ wout,
                 u16* __restrict__ FbT){
  const int b = blockIdx.x >> 5;
  const int c0 = (blockIdx.x & 31) * 32;
  const int t = threadIdx.x;
  __shared__ float cs[4 * 1032];          // +8 pad per head: no 2-addr bank clash
  #pragma unroll
  for (int i = 0; i < 16; i++){
    int idx = i * 256 + t;                // 0..4095 = h*1024 + (e*32+d)
    cs[(idx >> 10) * 1032 + (idx & 1023)] = ctxT[(size_t)b * 4096 + idx];
  }
  __syncthreads();
  const int c  = c0 + (t & 31);
  const int h  = (t >> 5) & 3;
  const int d0 = (t >> 7) * 16;
  float we[32];
  #pragma unroll
  for (int e = 0; e < 32; e++) we[e] = wout[(size_t)(h*32 + e) * 1024 + c];
  #pragma unroll 4
  for (int d = 0; d < 16; d++){
    float a = 0.f;
    #pragma unroll
    for (int e = 0; e < 32; e++) a += cs[h*1032 + e*32 + (d0 + d)] * we[e];
    FbT[((size_t)b * 1024 + c) * HID + h*32 + d0 + d] = f2bf(a);
  }
}

// ---------------------------------------------------------------------------
// 6. Final GEMM: out[M x 1024] = qb[M x 128] * FbT[b][1024 x 128]^T + bias + x
//    (attn never materialized: ctx folded into weights). K=128 one-shot,
//    128x128 tile, 2x2 waves, per-batch B selected by rowTile.
// ---------------------------------------------------------------------------
__global__ __launch_bounds__(256)
void gemm_out(const u16* __restrict__ A, const u16* __restrict__ Bt,
              float* __restrict__ C, const float* __restrict__ bias,
              const float* __restrict__ resid){
  __shared__ __align__(16) u16 As[128 * 128];  // 32 KB
  __shared__ __align__(16) u16 Bs[128 * 128];  // 32 KB
  const int t = threadIdx.x, lane = t & 63, w = t >> 6;
  const int rowTile = blockIdx.y * 128, colTile = blockIdx.x * 128;
  const u16* Bt_b = Bt + (size_t)(rowTile >> 12) * (1024 * HID);  // per-batch F
  const int r4 = lane >> 4;                       // row within 4-row group
  u16* dA = &As[w * 32 * 128];
  u16* dB = &Bs[w * 32 * 128];
  #pragma unroll
  for (int j = 0; j < 8; j++){
    int i = w * 8 + j;
    int lcw = (lane & 15) ^ ((4 * (i & 1)) | r4);  // logical chunk (row&7 swizzle)
    const u16* gA = A    + (size_t)(rowTile + i*4 + r4) * 128 + lcw * 8;
    const u16* gB = Bt_b + (size_t)(colTile + i*4 + r4) * 128 + lcw * 8;
    GLOAD_LDS16(gA, dA + j * 4 * 128);
    GLOAD_LDS16(gB, dB + j * 4 * 128);
  }
  const int wr = (w >> 1) * 64, wc = (w & 1) * 64;
  const int fr = lane & 15, q = lane >> 4;
  f32x4 acc[4][4];
  #pragma unroll
  for (int i = 0; i < 4; i++)
    #pragma unroll
    for (int j = 0; j < 4; j++)
      #pragma unroll
      for (int r = 0; r < 4; r++) acc[i][j][r] = 0.f;
  __syncthreads();
  #pragma unroll
  for (int kk = 0; kk < 4; kk++){
    bf16x8 af[4], bf[4];
    #pragma unroll
    for (int mi = 0; mi < 4; mi++){
      int pcc = ((kk*4 + q) ^ (fr & 7)) * 8;
      af[mi] = *(const bf16x8*)&As[(wr + mi*16 + fr) * 128 + pcc];
    }
    #pragma unroll
    for (int ni = 0; ni < 4; ni++){
      int pcc = ((kk*4 + q) ^ (fr & 7)) * 8;
      bf[ni] = *(const bf16x8*)&Bs[(wc + ni*16 + fr) * 128 + pcc];
    }
    #pragma unroll
    for (int mi = 0; mi < 4; mi++)
      #pragma unroll
      for (int ni = 0; ni < 4; ni++)
        acc[mi][ni] = __builtin_amdgcn_mfma_f32_16x16x32_bf16(af[mi], bf[ni], acc[mi][ni], 0, 0, 0);
  }
  #pragma unroll
  for (int mi = 0; mi < 4; mi++){
    #pragma unroll
    for (int ni = 0; ni < 4; ni++){
      #pragma unroll
      for (int r = 0; r < 4; r++){
        int row = rowTile + wr + mi*16 + q*4 + r;
        int col = colTile + wc + ni*16 + fr;
        C[(size_t)row * D_ + col] =
            acc[mi][ni][r] + bias[col] + resid[(size_t)row * D_ + col];
      }
    }
  }
}

// ---------------------------------------------------------------------------
// Launch. d_out reuse: [0,64MB)=xn bf16, [64,96MB)=kv fp32 (both dead before
// gemm_out overwrites d_out).
// ws (11.7 MB, same footprint as before):
//   wqT @0 (768K) | pctx/FbT @0x100000 (2M, disjoint lifetimes) |
//   psum @0x300000 (64K) | ctxT @0x310000 (128K) | qb @0x330000 (8M)
// ---------------------------------------------------------------------------
extern "C" void kernel_launch(void* const* d_in, const int* in_sizes, int n_in,
                              void* d_out, int out_size, void* d_ws, size_t ws_size,
                              hipStream_t stream){
  const float* x     = (const float*)d_in[0];
  const float* gamma = (const float*)d_in[1];
  const float* beta  = (const float*)d_in[2];
  const float* wqkv  = (const float*)d_in[3];
  const float* wout  = (const float*)d_in[4];
  const float* bout  = (const float*)d_in[5];
  float* out = (float*)d_out;

  char* ob  = (char*)d_out;
  u16*   xn = (u16*)ob;                               // 64 MB
  float* kv = (float*)(ob + (size_t)M_ * D_ * 2);     // 32 MB

  char* wsb = (char*)d_ws;
  u16*   wqT  = (u16*)  (wsb);                 // 768 KB
  float* pctx = (float*)(wsb + 0x00100000);    // 2 MB
  u16*   FbT  = (u16*)  (wsb + 0x00100000);    // 2 MB (aliases pctx; pctx dead)
  float* psum = (float*)(wsb + 0x00300000);    // 64 KB
  float* ctxT = (float*)(wsb + 0x00310000);    // 128 KB
  u16*   qb   = (u16*)  (wsb + 0x00330000);    // 8 MB

  convw_kernel<<<1536, 256, 0, stream>>>(wqkv, wqT);
  ln_kernel<<<M_/4, 256, 0, stream>>>(x, gamma, beta, xn);
  gemm_qkv<<<dim3(2, M_/128), 256, 0, stream>>>(xn, wqT, qb, kv);
  ctx_partial<<<dim3(16, 4, 8), 256, 0, stream>>>(kv, pctx, psum);
  ctx_reduce<<<32, 1024, 0, stream>>>(pctx, psum, ctxT);
  fold_kernel<<<256, 256, 0, stream>>>(ctxT, wout, FbT);
  gemm_out<<<dim3(D_/128, M_/128), 256, 0, stream>>>(qb, FbT, out, bout, x);
}

// Round 2
// 339.432 us; speedup vs baseline: 1.1152x; 1.1152x over previous
//
#include <hip/hip_runtime.h>

#define B_   8
#define N_   4096
#define D_   1024
#define HID  128
#define QKVW 384
#define M_   (B_*N_)   // 32768 rows

typedef unsigned short u16;
typedef unsigned int   u32;
typedef __attribute__((ext_vector_type(8))) short bf16x8;
typedef __attribute__((ext_vector_type(4))) float f32x4;

__device__ __forceinline__ u16 f2bf(float f){
  u32 u = __float_as_uint(f);
  u32 r = (u + 0x7fffu + ((u >> 16) & 1u)) >> 16;   // RNE
  return (u16)r;
}

// async global->LDS, 16B per lane; LDS dst = wave-uniform base + lane*16
#define GLOAD_LDS16(g, l) __builtin_amdgcn_global_load_lds( \
    (const __attribute__((address_space(1))) unsigned int*)(g), \
    (__attribute__((address_space(3))) unsigned int*)(l), 16, 0, 0)

// ---------------------------------------------------------------------------
// 0. QKV weights -> bf16, k-contiguous transposed (wout stays fp32; consumed
//    by fold_kernel directly)
// ---------------------------------------------------------------------------
__global__ void convw_kernel(const float* __restrict__ wqkv, u16* __restrict__ wqT){
  int idx = blockIdx.x * 256 + threadIdx.x;
  if (idx < QKVW * D_){
    int n = idx >> 10, k = idx & 1023;
    wqT[idx] = f2bf(wqkv[(size_t)k * QKVW + n]);
  }
}

// ---------------------------------------------------------------------------
// 1. LayerNorm over dim=1024. Wave-per-row, 4 rows/block, NO barriers:
//    64 lanes x 16 floats, 6-step butterfly shfl_xor reduce.
// ---------------------------------------------------------------------------
__global__ __launch_bounds__(256)
void ln_kernel(const float* __restrict__ x, const float* __restrict__ gamma,
               const float* __restrict__ beta, u16* __restrict__ xn){
  const int wid = threadIdx.x >> 6, lane = threadIdx.x & 63;
  const size_t row = (size_t)blockIdx.x * 4 + wid;
  const float4* xr = (const float4*)(x + row * D_);
  float4 v[4];
  float s = 0.f, q = 0.f;
  #pragma unroll
  for (int j = 0; j < 4; j++){
    v[j] = xr[j*64 + lane];
    s += v[j].x + v[j].y + v[j].z + v[j].w;
    q += v[j].x*v[j].x + v[j].y*v[j].y + v[j].z*v[j].z + v[j].w*v[j].w;
  }
  #pragma unroll
  for (int off = 32; off > 0; off >>= 1){
    s += __shfl_xor(s, off, 64);
    q += __shfl_xor(q, off, 64);
  }
  const float mean = s * (1.f / D_);
  const float rstd = rsqrtf(q * (1.f / D_) - mean * mean + 1e-5f);
  uint2* xo = (uint2*)(xn + row * D_);
  #pragma unroll
  for (int j = 0; j < 4; j++){
    const float4 g  = ((const float4*)gamma)[j*64 + lane];
    const float4 be = ((const float4*)beta)[j*64 + lane];
    float y0 = (v[j].x - mean) * rstd * g.x + be.x;
    float y1 = (v[j].y - mean) * rstd * g.y + be.y;
    float y2 = (v[j].z - mean) * rstd * g.z + be.z;
    float y3 = (v[j].w - mean) * rstd * g.w + be.w;
    uint2 o;
    o.x = (u32)f2bf(y0) | ((u32)f2bf(y1) << 16);
    o.y = (u32)f2bf(y2) | ((u32)f2bf(y3) << 16);
    xo[j*64 + lane] = o;
  }
}

// ---------------------------------------------------------------------------
// 2. QKV GEMM: [M x 384] = xn[M x 1024] * wqT[384 x 1024]^T
//    Tile 128x192, grid (2, M/128), XCD-chunked block swizzle (A-sharing
//    pairs land on the same XCD's L2).
//    DOUBLE-BUFFERED 2-phase (T3 minimum recipe): STAGE(next) is issued
//    BEFORE ds_read+MFMA of current buffer, so global-load latency hides
//    under compute; single vmcnt(0)+barrier per K-step.
//    Per wave per K-step: 5 gloads / 10 ds_read_b128 / 24 MFMA.
// ---------------------------------------------------------------------------
__device__ __forceinline__ void qkv_compute(const u16* __restrict__ Asb,
                                            const u16* __restrict__ Bsb,
                                            int wr, int wc, int fr, int pc,
                                            f32x4 acc[4][6]){
  bf16x8 af[4], bf[6];
  #pragma unroll
  for (int mi = 0; mi < 4; mi++) af[mi] = *(const bf16x8*)&Asb[(wr + mi*16 + fr)*32 + pc];
  #pragma unroll
  for (int ni = 0; ni < 6; ni++) bf[ni] = *(const bf16x8*)&Bsb[(wc + ni*16 + fr)*32 + pc];
  #pragma unroll
  for (int mi = 0; mi < 4; mi++)
    #pragma unroll
    for (int ni = 0; ni < 6; ni++)
      acc[mi][ni] = __builtin_amdgcn_mfma_f32_16x16x32_bf16(af[mi], bf[ni], acc[mi][ni], 0, 0, 0);
}

__global__ __launch_bounds__(256)
void gemm_qkv(const u16* __restrict__ A, const u16* __restrict__ Bt,
              u16* __restrict__ qb, float* __restrict__ kv){
  __shared__ __align__(16) u16 As[2][128 * 32];   // 2 x 8 KB
  __shared__ __align__(16) u16 Bs[2][192 * 32];   // 2 x 12 KB
  const int t = threadIdx.x, lane = t & 63, w = t >> 6;
  // XCD-chunked bijective swizzle: 512 wgs = 8 XCDs x 64
  const int lin = blockIdx.x + blockIdx.y * 2;
  const int vid = (lin & 7) * 64 + (lin >> 3);
  const int rowTile = (vid >> 1) * 128;
  const int colTile = (vid & 1) * 192;
  // staging: lane covers row lr, phys chunk lane&3, logical chunk lc
  const int lr = lane >> 2;
  const int lc = (lane & 3) ^ ((lane >> 3) & 3);       // phys ^ ((row>>1)&3)
  const u16* pA0 = A  + (size_t)(rowTile + (w*2)*16 + lr) * 1024 + lc * 8;
  const u16* pA1 = pA0 + 16 * 1024;
  const u16* pB0 = Bt + (size_t)(colTile + (w*3)*16 + lr) * 1024 + lc * 8;
  const u16* pB1 = pB0 + 16 * 1024;
  const u16* pB2 = pB0 + 32 * 1024;
  const int dAoff = (w*2) * 512;     // 512 u16 = 16 rows x 32
  const int dBoff = (w*3) * 512;
  const int fr = lane & 15, q = lane >> 4;
  const int pc = (q ^ ((fr >> 1) & 3)) * 8;            // phys chunk (halfwords)
  const int wr = (w >> 1) * 64, wc = (w & 1) * 96;

#define QKV_STAGE(bb) do{ \
    GLOAD_LDS16(pA0, &As[bb][dAoff      ]); \
    GLOAD_LDS16(pA1, &As[bb][dAoff + 512]); \
    GLOAD_LDS16(pB0, &Bs[bb][dBoff       ]); \
    GLOAD_LDS16(pB1, &Bs[bb][dBoff +  512]); \
    GLOAD_LDS16(pB2, &Bs[bb][dBoff + 1024]); \
    pA0 += 32; pA1 += 32; pB0 += 32; pB1 += 32; pB2 += 32; \
  }while(0)

  f32x4 acc[4][6];
  #pragma unroll
  for (int i = 0; i < 4; i++)
    #pragma unroll
    for (int j = 0; j < 6; j++)
      #pragma unroll
      for (int r = 0; r < 4; r++) acc[i][j][r] = 0.f;

  // prologue: stage K-step 0 into buf 0
  QKV_STAGE(0);
  asm volatile("s_waitcnt vmcnt(0)" ::: "memory");
  __syncthreads();

  // steady state: 15 x (stage(1)/compute(0); stage(0)/compute(1)) covers
  // K-steps 0..29 compute, 1..30 stage
  for (int it = 0; it < 15; ++it){
    QKV_STAGE(1);
    qkv_compute(As[0], Bs[0], wr, wc, fr, pc, acc);
    asm volatile("s_waitcnt vmcnt(0)" ::: "memory");
    __syncthreads();
    QKV_STAGE(0);
    qkv_compute(As[1], Bs[1], wr, wc, fr, pc, acc);
    asm volatile("s_waitcnt vmcnt(0)" ::: "memory");
    __syncthreads();
  }
  // it=30: stage last K-step (31) into buf 1, compute buf 0
  QKV_STAGE(1);
  qkv_compute(As[0], Bs[0], wr, wc, fr, pc, acc);
  asm volatile("s_waitcnt vmcnt(0)" ::: "memory");
  __syncthreads();
  // it=31: compute buf 1, no stage, no trailing sync needed
  qkv_compute(As[1], Bs[1], wr, wc, fr, pc, acc);
#undef QKV_STAGE

  #pragma unroll
  for (int mi = 0; mi < 4; mi++){
    #pragma unroll
    for (int ni = 0; ni < 6; ni++){
      #pragma unroll
      for (int r = 0; r < 4; r++){
        int row = rowTile + wr + mi*16 + q*4 + r;
        int col = colTile + wc + ni*16 + fr;
        float val = acc[mi][ni][r];
        if (col < HID) qb[(size_t)row * HID + col] = f2bf(val);   // q, bf16
        else           kv[(size_t)row * 256 + (col - HID)] = val; // k,v fp32
      }
    }
  }
}

// ---------------------------------------------------------------------------
// 3. Softmax/context partials per (256-row chunk, head, batch). 512 blocks.
//    kv layout: [row][256] fp32, k = cols 0..127, v = cols 128..255.
// ---------------------------------------------------------------------------
__global__ __launch_bounds__(256)
void ctx_partial(const float* __restrict__ kv, float* __restrict__ pctx,
                 float* __restrict__ psum){
  const int c = blockIdx.x, h = blockIdx.y, b = blockIdx.z;
  const int t = threadIdx.x;
  __shared__ float ek[64][32], vv[64][32];
  const int d = t >> 3, e0 = (t & 7) * 4;
  const int rl = t >> 2, cg = (t & 3) * 8;
  float a0=0.f, a1=0.f, a2=0.f, a3=0.f, ks=0.f;
  const size_t rowbase = (size_t)b * N_ + (size_t)c * 256;
  for (int s = 0; s < 4; ++s){
    __syncthreads();
    const float* src = kv + (rowbase + s*64 + rl) * 256 + h*32 + cg;
    float4 ka = *(const float4*)(src);
    float4 kb = *(const float4*)(src + 4);
    float4 va = *(const float4*)(src + 128);
    float4 vb = *(const float4*)(src + 132);
    float4 ea = make_float4(__expf(ka.x), __expf(ka.y), __expf(ka.z), __expf(ka.w));
    float4 eb = make_float4(__expf(kb.x), __expf(kb.y), __expf(kb.z), __expf(kb.w));
    *(float4*)&ek[rl][cg]     = ea;
    *(float4*)&ek[rl][cg + 4] = eb;
    *(float4*)&vv[rl][cg]     = va;
    *(float4*)&vv[rl][cg + 4] = vb;
    __syncthreads();
    #pragma unroll 8
    for (int n = 0; n < 64; ++n){
      float kd = ek[n][d];
      float4 vn = *(const float4*)&vv[n][e0];
      a0 += kd * vn.x; a1 += kd * vn.y; a2 += kd * vn.z; a3 += kd * vn.w;
      ks += kd;
    }
  }
  float* op = pctx + (((size_t)(b*4 + h) * 16 + c) * 1024) + d*32 + e0;
  *(float4*)op = make_float4(a0, a1, a2, a3);
  if (e0 == 0) psum[((size_t)(b*4 + h) * 16 + c) * 32 + d] = ks;
}

// ---------------------------------------------------------------------------
// 4. Reduce partials -> ctxT[bh][e*32+d] (normalized, q-scale folded)
// ---------------------------------------------------------------------------
__global__ void ctx_reduce(const float* __restrict__ pctx, const float* __restrict__ psum,
                           float* __restrict__ ctxT){
  int bh = blockIdx.x, t = threadIdx.x;   // 1024 threads: t = d*32 + e
  int d = t >> 5, e = t & 31;
  float s = 0.f, S = 0.f;
  for (int c = 0; c < 16; ++c){
    s += pctx[((size_t)bh * 16 + c) * 1024 + t];
    S += psum[((size_t)bh * 16 + c) * 32 + d];
  }
  ctxT[(size_t)bh * 1024 + e*32 + d] = s / S * 0.17677669529663689f; // * 32^-0.5
}

// ---------------------------------------------------------------------------
// 5. Fold context into output weights:
//    FbT[b][c][h*32+d] = sum_e ctxT[b*4+h][e*32+d] * wout[(h*32+e)*1024 + c]
//    (bf16, k-contiguous B operand for the final GEMM). 33M MACs total.
// ---------------------------------------------------------------------------
__global__ __launch_bounds__(256)
void fold_kernel(const float* __restrict__ ctxT, const float* __restrict__ wout,
                 u16* __restrict__ FbT){
  const int b = blockIdx.x >> 5;
  const int c0 = (blockIdx.x & 31) * 32;
  const int t = threadIdx.x;
  __shared__ float cs[4 * 1032];          // +8 pad per head: no 2-addr bank clash
  #pragma unroll
  for (int i = 0; i < 16; i++){
    int idx = i * 256 + t;                // 0..4095 = h*1024 + (e*32+d)
    cs[(idx >> 10) * 1032 + (idx & 1023)] = ctxT[(size_t)b * 4096 + idx];
  }
  __syncthreads();
  const int c  = c0 + (t & 31);
  const int h  = (t >> 5) & 3;
  const int d0 = (t >> 7) * 16;
  float we[32];
  #pragma unroll
  for (int e = 0; e < 32; e++) we[e] = wout[(size_t)(h*32 + e) * 1024 + c];
  #pragma unroll 4
  for (int d = 0; d < 16; d++){
    float a = 0.f;
    #pragma unroll
    for (int e = 0; e < 32; e++) a += cs[h*1032 + e*32 + (d0 + d)] * we[e];
    FbT[((size_t)b * 1024 + c) * HID + h*32 + d0 + d] = f2bf(a);
  }
}

// ---------------------------------------------------------------------------
// 6. Final GEMM: out[M x 1024] = qb[M x 128] * FbT[b][1024 x 128]^T + bias + x
//    (attn never materialized: ctx folded into weights). K=128 one-shot,
//    128x128 tile, 2x2 waves, per-batch B selected by rowTile.
// ---------------------------------------------------------------------------
__global__ __launch_bounds__(256)
void gemm_out(const u16* __restrict__ A, const u16* __restrict__ Bt,
              float* __restrict__ C, const float* __restrict__ bias,
              const float* __restrict__ resid){
  __shared__ __align__(16) u16 As[128 * 128];  // 32 KB
  __shared__ __align__(16) u16 Bs[128 * 128];  // 32 KB
  const int t = threadIdx.x, lane = t & 63, w = t >> 6;
  const int rowTile = blockIdx.y * 128, colTile = blockIdx.x * 128;
  const u16* Bt_b = Bt + (size_t)(rowTile >> 12) * (1024 * HID);  // per-batch F
  const int r4 = lane >> 4;                       // row within 4-row group
  u16* dA = &As[w * 32 * 128];
  u16* dB = &Bs[w * 32 * 128];
  #pragma unroll
  for (int j = 0; j < 8; j++){
    int i = w * 8 + j;
    int lcw = (lane & 15) ^ ((4 * (i & 1)) | r4);  // logical chunk (row&7 swizzle)
    const u16* gA = A    + (size_t)(rowTile + i*4 + r4) * 128 + lcw * 8;
    const u16* gB = Bt_b + (size_t)(colTile + i*4 + r4) * 128 + lcw * 8;
    GLOAD_LDS16(gA, dA + j * 4 * 128);
    GLOAD_LDS16(gB, dB + j * 4 * 128);
  }
  const int wr = (w >> 1) * 64, wc = (w & 1) * 64;
  const int fr = lane & 15, q = lane >> 4;
  f32x4 acc[4][4];
  #pragma unroll
  for (int i = 0; i < 4; i++)
    #pragma unroll
    for (int j = 0; j < 4; j++)
      #pragma unroll
      for (int r = 0; r < 4; r++) acc[i][j][r] = 0.f;
  __syncthreads();
  #pragma unroll
  for (int kk = 0; kk < 4; kk++){
    bf16x8 af[4], bf[4];
    #pragma unroll
    for (int mi = 0; mi < 4; mi++){
      int pcc = ((kk*4 + q) ^ (fr & 7)) * 8;
      af[mi] = *(const bf16x8*)&As[(wr + mi*16 + fr) * 128 + pcc];
    }
    #pragma unroll
    for (int ni = 0; ni < 4; ni++){
      int pcc = ((kk*4 + q) ^ (fr & 7)) * 8;
      bf[ni] = *(const bf16x8*)&Bs[(wc + ni*16 + fr) * 128 + pcc];
    }
    #pragma unroll
    for (int mi = 0; mi < 4; mi++)
      #pragma unroll
      for (int ni = 0; ni < 4; ni++)
        acc[mi][ni] = __builtin_amdgcn_mfma_f32_16x16x32_bf16(af[mi], bf[ni], acc[mi][ni], 0, 0, 0);
  }
  #pragma unroll
  for (int mi = 0; mi < 4; mi++){
    #pragma unroll
    for (int ni = 0; ni < 4; ni++){
      #pragma unroll
      for (int r = 0; r < 4; r++){
        int row = rowTile + wr + mi*16 + q*4 + r;
        int col = colTile + wc + ni*16 + fr;
        C[(size_t)row * D_ + col] =
            acc[mi][ni][r] + bias[col] + resid[(size_t)row * D_ + col];
      }
    }
  }
}

// ---------------------------------------------------------------------------
// Launch. d_out reuse: [0,64MB)=xn bf16, [64,96MB)=kv fp32 (both dead before
// gemm_out overwrites d_out).
// ws (11.7 MB):
//   wqT @0 (768K) | pctx/FbT @0x100000 (2M, disjoint lifetimes) |
//   psum @0x300000 (64K) | ctxT @0x310000 (128K) | qb @0x330000 (8M)
// ---------------------------------------------------------------------------
extern "C" void kernel_launch(void* const* d_in, const int* in_sizes, int n_in,
                              void* d_out, int out_size, void* d_ws, size_t ws_size,
                              hipStream_t stream){
  const float* x     = (const float*)d_in[0];
  const float* gamma = (const float*)d_in[1];
  const float* beta  = (const float*)d_in[2];
  const float* wqkv  = (const float*)d_in[3];
  const float* wout  = (const float*)d_in[4];
  const float* bout  = (const float*)d_in[5];
  float* out = (float*)d_out;

  char* ob  = (char*)d_out;
  u16*   xn = (u16*)ob;                               // 64 MB
  float* kv = (float*)(ob + (size_t)M_ * D_ * 2);     // 32 MB

  char* wsb = (char*)d_ws;
  u16*   wqT  = (u16*)  (wsb);                 // 768 KB
  float* pctx = (float*)(wsb + 0x00100000);    // 2 MB
  u16*   FbT  = (u16*)  (wsb + 0x00100000);    // 2 MB (aliases pctx; pctx dead)
  float* psum = (float*)(wsb + 0x00300000);    // 64 KB
  float* ctxT = (float*)(wsb + 0x00310000);    // 128 KB
  u16*   qb   = (u16*)  (wsb + 0x00330000);    // 8 MB

  convw_kernel<<<1536, 256, 0, stream>>>(wqkv, wqT);
  ln_kernel<<<M_/4, 256, 0, stream>>>(x, gamma, beta, xn);
  gemm_qkv<<<dim3(2, M_/128), 256, 0, stream>>>(xn, wqT, qb, kv);
  ctx_partial<<<dim3(16, 4, 8), 256, 0, stream>>>(kv, pctx, psum);
  ctx_reduce<<<32, 1024, 0, stream>>>(pctx, psum, ctxT);
  fold_kernel<<<256, 256, 0, stream>>>(ctxT, wout, FbT);
  gemm_out<<<dim3(D_/128, M_/128), 256, 0, stream>>>(qb, FbT, out, bout, x);
}

// Round 3
// 334.351 us; speedup vs baseline: 1.1321x; 1.0152x over previous
//
#include <hip/hip_runtime.h>

#define B_   8
#define N_   4096
#define D_   1024
#define HID  128
#define QKVW 384
#define M_   (B_*N_)   // 32768 rows

typedef unsigned short u16;
typedef unsigned int   u32;
typedef __attribute__((ext_vector_type(8))) short bf16x8;
typedef __attribute__((ext_vector_type(4))) float f32x4;

__device__ __forceinline__ u16 f2bf(float f){
  u32 u = __float_as_uint(f);
  u32 r = (u + 0x7fffu + ((u >> 16) & 1u)) >> 16;   // RNE
  return (u16)r;
}

// async global->LDS, 16B per lane; LDS dst = wave-uniform base + lane*16
#define GLOAD_LDS16(g, l) __builtin_amdgcn_global_load_lds( \
    (const __attribute__((address_space(1))) unsigned int*)(g), \
    (__attribute__((address_space(3))) unsigned int*)(l), 16, 0, 0)

// ---------------------------------------------------------------------------
// 0. QKV weights -> bf16, k-contiguous transposed
// ---------------------------------------------------------------------------
__global__ void convw_kernel(const float* __restrict__ wqkv, u16* __restrict__ wqT){
  int idx = blockIdx.x * 256 + threadIdx.x;
  if (idx < QKVW * D_){
    int n = idx >> 10, k = idx & 1023;
    wqT[idx] = f2bf(wqkv[(size_t)k * QKVW + n]);
  }
}

// ---------------------------------------------------------------------------
// 1. LayerNorm over dim=1024. Wave-per-row, 4 rows/block, NO barriers.
// ---------------------------------------------------------------------------
__global__ __launch_bounds__(256)
void ln_kernel(const float* __restrict__ x, const float* __restrict__ gamma,
               const float* __restrict__ beta, u16* __restrict__ xn){
  const int wid = threadIdx.x >> 6, lane = threadIdx.x & 63;
  const size_t row = (size_t)blockIdx.x * 4 + wid;
  const float4* xr = (const float4*)(x + row * D_);
  float4 v[4];
  float s = 0.f, q = 0.f;
  #pragma unroll
  for (int j = 0; j < 4; j++){
    v[j] = xr[j*64 + lane];
    s += v[j].x + v[j].y + v[j].z + v[j].w;
    q += v[j].x*v[j].x + v[j].y*v[j].y + v[j].z*v[j].z + v[j].w*v[j].w;
  }
  #pragma unroll
  for (int off = 32; off > 0; off >>= 1){
    s += __shfl_xor(s, off, 64);
    q += __shfl_xor(q, off, 64);
  }
  const float mean = s * (1.f / D_);
  const float rstd = rsqrtf(q * (1.f / D_) - mean * mean + 1e-5f);
  uint2* xo = (uint2*)(xn + row * D_);
  #pragma unroll
  for (int j = 0; j < 4; j++){
    const float4 g  = ((const float4*)gamma)[j*64 + lane];
    const float4 be = ((const float4*)beta)[j*64 + lane];
    float y0 = (v[j].x - mean) * rstd * g.x + be.x;
    float y1 = (v[j].y - mean) * rstd * g.y + be.y;
    float y2 = (v[j].z - mean) * rstd * g.z + be.z;
    float y3 = (v[j].w - mean) * rstd * g.w + be.w;
    uint2 o;
    o.x = (u32)f2bf(y0) | ((u32)f2bf(y1) << 16);
    o.y = (u32)f2bf(y2) | ((u32)f2bf(y3) << 16);
    xo[j*64 + lane] = o;
  }
}

// ---------------------------------------------------------------------------
// 2. QKV GEMM: [M x 384] = xn[M x 1024] * wqT[384 x 1024]^T
//    Tile 128x192, grid (2, M/128), XCD-chunked swizzle.
//    3-buffer pipeline (T3+T4): ONE raw s_barrier per K-step, counted
//    vmcnt(5) -- next-next tile's 5 loads stay in flight across the barrier.
//    Phase p: STAGE buf[(p+2)%3] (tile k+2), compute buf[p] (tile k),
//    vmcnt(5) drains tile k+1, barrier, sched_barrier(0) pins ordering.
// ---------------------------------------------------------------------------
__device__ __forceinline__ void qkv_compute(const u16* __restrict__ Asb,
                                            const u16* __restrict__ Bsb,
                                            int wr, int wc, int fr, int pc,
                                            f32x4 acc[4][6]){
  bf16x8 af[4], bf[6];
  #pragma unroll
  for (int mi = 0; mi < 4; mi++) af[mi] = *(const bf16x8*)&Asb[(wr + mi*16 + fr)*32 + pc];
  #pragma unroll
  for (int ni = 0; ni < 6; ni++) bf[ni] = *(const bf16x8*)&Bsb[(wc + ni*16 + fr)*32 + pc];
  #pragma unroll
  for (int mi = 0; mi < 4; mi++)
    #pragma unroll
    for (int ni = 0; ni < 6; ni++)
      acc[mi][ni] = __builtin_amdgcn_mfma_f32_16x16x32_bf16(af[mi], bf[ni], acc[mi][ni], 0, 0, 0);
}

__global__ __launch_bounds__(256)
void gemm_qkv(const u16* __restrict__ A, const u16* __restrict__ Bt,
              u16* __restrict__ qb, float* __restrict__ kv){
  __shared__ __align__(16) u16 As[3][128 * 32];   // 3 x 8 KB
  __shared__ __align__(16) u16 Bs[3][192 * 32];   // 3 x 12 KB  (60 KB total)
  const int t = threadIdx.x, lane = t & 63, w = t >> 6;
  // XCD-chunked bijective swizzle: 512 wgs = 8 XCDs x 64
  const int lin = blockIdx.x + blockIdx.y * 2;
  const int vid = (lin & 7) * 64 + (lin >> 3);
  const int rowTile = (vid >> 1) * 128;
  const int colTile = (vid & 1) * 192;
  const int lr = lane >> 2;
  const int lc = (lane & 3) ^ ((lane >> 3) & 3);       // phys ^ ((row>>1)&3)
  const u16* pA0 = A  + (size_t)(rowTile + (w*2)*16 + lr) * 1024 + lc * 8;
  const u16* pA1 = pA0 + 16 * 1024;
  const u16* pB0 = Bt + (size_t)(colTile + (w*3)*16 + lr) * 1024 + lc * 8;
  const u16* pB1 = pB0 + 16 * 1024;
  const u16* pB2 = pB0 + 32 * 1024;
  const int dAoff = (w*2) * 512;     // 512 u16 = 16 rows x 32
  const int dBoff = (w*3) * 512;
  const int fr = lane & 15, q = lane >> 4;
  const int pc = (q ^ ((fr >> 1) & 3)) * 8;            // phys chunk (halfwords)
  const int wr = (w >> 1) * 64, wc = (w & 1) * 96;

#define QKV_STAGE(bb) do{ \
    GLOAD_LDS16(pA0, &As[bb][dAoff      ]); \
    GLOAD_LDS16(pA1, &As[bb][dAoff + 512]); \
    GLOAD_LDS16(pB0, &Bs[bb][dBoff       ]); \
    GLOAD_LDS16(pB1, &Bs[bb][dBoff +  512]); \
    GLOAD_LDS16(pB2, &Bs[bb][dBoff + 1024]); \
    pA0 += 32; pA1 += 32; pB0 += 32; pB1 += 32; pB2 += 32; \
  }while(0)
#define QKV_SYNC5 do{ \
    asm volatile("s_waitcnt vmcnt(5)" ::: "memory"); \
    __builtin_amdgcn_s_barrier(); \
    __builtin_amdgcn_sched_barrier(0); \
  }while(0)

  f32x4 acc[4][6];
  #pragma unroll
  for (int i = 0; i < 4; i++)
    #pragma unroll
    for (int j = 0; j < 6; j++)
      #pragma unroll
      for (int r = 0; r < 4; r++) acc[i][j][r] = 0.f;

  // prologue: tiles 0,1 staged; drain tile 0 (vmcnt(5)), barrier
  QKV_STAGE(0);
  QKV_STAGE(1);
  QKV_SYNC5;
  // steady state: steps 0..29 (10 iters x 3 phases), tile k from buf k%3
  for (int it = 0; it < 10; ++it){
    QKV_STAGE(2); qkv_compute(As[0], Bs[0], wr, wc, fr, pc, acc); QKV_SYNC5;
    QKV_STAGE(0); qkv_compute(As[1], Bs[1], wr, wc, fr, pc, acc); QKV_SYNC5;
    QKV_STAGE(1); qkv_compute(As[2], Bs[2], wr, wc, fr, pc, acc); QKV_SYNC5;
  }
  // step 30: compute tile30 (buf0); drain tile31 fully; barrier
  qkv_compute(As[0], Bs[0], wr, wc, fr, pc, acc);
  asm volatile("s_waitcnt vmcnt(0)" ::: "memory");
  __builtin_amdgcn_s_barrier();
  __builtin_amdgcn_sched_barrier(0);
  // step 31: compute tile31 (buf1)
  qkv_compute(As[1], Bs[1], wr, wc, fr, pc, acc);
#undef QKV_STAGE
#undef QKV_SYNC5

  #pragma unroll
  for (int mi = 0; mi < 4; mi++){
    #pragma unroll
    for (int ni = 0; ni < 6; ni++){
      #pragma unroll
      for (int r = 0; r < 4; r++){
        int row = rowTile + wr + mi*16 + q*4 + r;
        int col = colTile + wc + ni*16 + fr;
        float val = acc[mi][ni][r];
        if (col < HID) qb[(size_t)row * HID + col] = f2bf(val);   // q, bf16
        else           kv[(size_t)row * 256 + (col - HID)] = val; // k,v fp32
      }
    }
  }
}

// ---------------------------------------------------------------------------
// 3. Softmax/context partials per (256-row chunk, head, batch). 512 blocks.
// ---------------------------------------------------------------------------
__global__ __launch_bounds__(256)
void ctx_partial(const float* __restrict__ kv, float* __restrict__ pctx,
                 float* __restrict__ psum){
  const int c = blockIdx.x, h = blockIdx.y, b = blockIdx.z;
  const int t = threadIdx.x;
  __shared__ float ek[64][32], vv[64][32];
  const int d = t >> 3, e0 = (t & 7) * 4;
  const int rl = t >> 2, cg = (t & 3) * 8;
  float a0=0.f, a1=0.f, a2=0.f, a3=0.f, ks=0.f;
  const size_t rowbase = (size_t)b * N_ + (size_t)c * 256;
  for (int s = 0; s < 4; ++s){
    __syncthreads();
    const float* src = kv + (rowbase + s*64 + rl) * 256 + h*32 + cg;
    float4 ka = *(const float4*)(src);
    float4 kb = *(const float4*)(src + 4);
    float4 va = *(const float4*)(src + 128);
    float4 vb = *(const float4*)(src + 132);
    float4 ea = make_float4(__expf(ka.x), __expf(ka.y), __expf(ka.z), __expf(ka.w));
    float4 eb = make_float4(__expf(kb.x), __expf(kb.y), __expf(kb.z), __expf(kb.w));
    *(float4*)&ek[rl][cg]     = ea;
    *(float4*)&ek[rl][cg + 4] = eb;
    *(float4*)&vv[rl][cg]     = va;
    *(float4*)&vv[rl][cg + 4] = vb;
    __syncthreads();
    #pragma unroll 8
    for (int n = 0; n < 64; ++n){
      float kd = ek[n][d];
      float4 vn = *(const float4*)&vv[n][e0];
      a0 += kd * vn.x; a1 += kd * vn.y; a2 += kd * vn.z; a3 += kd * vn.w;
      ks += kd;
    }
  }
  float* op = pctx + (((size_t)(b*4 + h) * 16 + c) * 1024) + d*32 + e0;
  *(float4*)op = make_float4(a0, a1, a2, a3);
  if (e0 == 0) psum[((size_t)(b*4 + h) * 16 + c) * 32 + d] = ks;
}

// ---------------------------------------------------------------------------
// 4. Reduce partials -> ctxT[bh][e*32+d] (normalized, q-scale folded)
// ---------------------------------------------------------------------------
__global__ void ctx_reduce(const float* __restrict__ pctx, const float* __restrict__ psum,
                           float* __restrict__ ctxT){
  int bh = blockIdx.x, t = threadIdx.x;   // 1024 threads: t = d*32 + e
  int d = t >> 5, e = t & 31;
  float s = 0.f, S = 0.f;
  for (int c = 0; c < 16; ++c){
    s += pctx[((size_t)bh * 16 + c) * 1024 + t];
    S += psum[((size_t)bh * 16 + c) * 32 + d];
  }
  ctxT[(size_t)bh * 1024 + e*32 + d] = s / S * 0.17677669529663689f; // * 32^-0.5
}

// ---------------------------------------------------------------------------
// 5. Fold context into output weights:
//    FbT[b][c][h*32+d] = sum_e ctxT[b*4+h][e*32+d] * wout[(h*32+e)*1024 + c]
// ---------------------------------------------------------------------------
__global__ __launch_bounds__(256)
void fold_kernel(const float* __restrict__ ctxT, const float* __restrict__ wout,
                 u16* __restrict__ FbT){
  const int b = blockIdx.x >> 5;
  const int c0 = (blockIdx.x & 31) * 32;
  const int t = threadIdx.x;
  __shared__ float cs[4 * 1032];          // +8 pad per head
  #pragma unroll
  for (int i = 0; i < 16; i++){
    int idx = i * 256 + t;                // 0..4095 = h*1024 + (e*32+d)
    cs[(idx >> 10) * 1032 + (idx & 1023)] = ctxT[(size_t)b * 4096 + idx];
  }
  __syncthreads();
  const int c  = c0 + (t & 31);
  const int h  = (t >> 5) & 3;
  const int d0 = (t >> 7) * 16;
  float we[32];
  #pragma unroll
  for (int e = 0; e < 32; e++) we[e] = wout[(size_t)(h*32 + e) * 1024 + c];
  #pragma unroll 4
  for (int d = 0; d < 16; d++){
    float a = 0.f;
    #pragma unroll
    for (int e = 0; e < 32; e++) a += cs[h*1032 + e*32 + (d0 + d)] * we[e];
    FbT[((size_t)b * 1024 + c) * HID + h*32 + d0 + d] = f2bf(a);
  }
}

// ---------------------------------------------------------------------------
// 6. Final GEMM: out[M x 1024] = qb[M x 128] * FbT[b][1024 x 128]^T + bias + x
//    XCD-chunked swizzle: each XCD handles exactly one batch (its 256 KB FbT
//    stays L2-resident; qb A-panels reused within-XCD). T14: resid/bias
//    prefetched into regs right after the barrier so the 64 scalar loads
//    hide under the 64 MFMAs.
// ---------------------------------------------------------------------------
__global__ __launch_bounds__(256)
void gemm_out(const u16* __restrict__ A, const u16* __restrict__ Bt,
              float* __restrict__ C, const float* __restrict__ bias,
              const float* __restrict__ resid){
  __shared__ __align__(16) u16 As[128 * 128];  // 32 KB
  __shared__ __align__(16) u16 Bs[128 * 128];  // 32 KB
  const int t = threadIdx.x, lane = t & 63, w = t >> 6;
  // bijective XCD-chunk swizzle: 2048 wgs = 8 XCDs x 256 (32 rowTiles x 8 colTiles)
  const int lin = blockIdx.x + blockIdx.y * 8;
  const int xcd = lin & 7, idx = lin >> 3;
  const int rowTile = (xcd * 32 + (idx >> 3)) * 128;
  const int colTile = (idx & 7) * 128;
  const u16* Bt_b = Bt + (size_t)(rowTile >> 12) * (1024 * HID);  // per-batch F
  const int r4 = lane >> 4;                       // row within 4-row group
  u16* dA = &As[w * 32 * 128];
  u16* dB = &Bs[w * 32 * 128];
  #pragma unroll
  for (int j = 0; j < 8; j++){
    int i = w * 8 + j;
    int lcw = (lane & 15) ^ ((4 * (i & 1)) | r4);  // logical chunk (row&7 swizzle)
    const u16* gA = A    + (size_t)(rowTile + i*4 + r4) * 128 + lcw * 8;
    const u16* gB = Bt_b + (size_t)(colTile + i*4 + r4) * 128 + lcw * 8;
    GLOAD_LDS16(gA, dA + j * 4 * 128);
    GLOAD_LDS16(gB, dB + j * 4 * 128);
  }
  const int wr = (w >> 1) * 64, wc = (w & 1) * 64;
  const int fr = lane & 15, q = lane >> 4;
  f32x4 acc[4][4];
  #pragma unroll
  for (int i = 0; i < 4; i++)
    #pragma unroll
    for (int j = 0; j < 4; j++)
      #pragma unroll
      for (int r = 0; r < 4; r++) acc[i][j][r] = 0.f;
  __syncthreads();
  // T14 prefetch: issue resid + bias loads now; latency hides under MFMAs
  float rbuf[4][4][4];   // [mi][r][ni]
  float bv[4];
  #pragma unroll
  for (int ni = 0; ni < 4; ni++) bv[ni] = bias[colTile + wc + ni*16 + fr];
  #pragma unroll
  for (int mi = 0; mi < 4; mi++)
    #pragma unroll
    for (int r = 0; r < 4; r++){
      const float* rp = resid + (size_t)(rowTile + wr + mi*16 + q*4 + r) * D_;
      #pragma unroll
      for (int ni = 0; ni < 4; ni++)
        rbuf[mi][r][ni] = rp[colTile + wc + ni*16 + fr];
    }
  #pragma unroll
  for (int kk = 0; kk < 4; kk++){
    bf16x8 af[4], bf[4];
    #pragma unroll
    for (int mi = 0; mi < 4; mi++){
      int pcc = ((kk*4 + q) ^ (fr & 7)) * 8;
      af[mi] = *(const bf16x8*)&As[(wr + mi*16 + fr) * 128 + pcc];
    }
    #pragma unroll
    for (int ni = 0; ni < 4; ni++){
      int pcc = ((kk*4 + q) ^ (fr & 7)) * 8;
      bf[ni] = *(const bf16x8*)&Bs[(wc + ni*16 + fr) * 128 + pcc];
    }
    #pragma unroll
    for (int mi = 0; mi < 4; mi++)
      #pragma unroll
      for (int ni = 0; ni < 4; ni++)
        acc[mi][ni] = __builtin_amdgcn_mfma_f32_16x16x32_bf16(af[mi], bf[ni], acc[mi][ni], 0, 0, 0);
  }
  #pragma unroll
  for (int mi = 0; mi < 4; mi++){
    #pragma unroll
    for (int ni = 0; ni < 4; ni++){
      #pragma unroll
      for (int r = 0; r < 4; r++){
        int row = rowTile + wr + mi*16 + q*4 + r;
        int col = colTile + wc + ni*16 + fr;
        C[(size_t)row * D_ + col] = acc[mi][ni][r] + bv[ni] + rbuf[mi][r][ni];
      }
    }
  }
}

// ---------------------------------------------------------------------------
// Launch. d_out reuse: [0,64MB)=xn bf16, [64,96MB)=kv fp32 (both dead before
// gemm_out overwrites d_out).
// ws (11.7 MB):
//   wqT @0 (768K) | pctx/FbT @0x100000 (2M, disjoint lifetimes) |
//   psum @0x300000 (64K) | ctxT @0x310000 (128K) | qb @0x330000 (8M)
// ---------------------------------------------------------------------------
extern "C" void kernel_launch(void* const* d_in, const int* in_sizes, int n_in,
                              void* d_out, int out_size, void* d_ws, size_t ws_size,
                              hipStream_t stream){
  const float* x     = (const float*)d_in[0];
  const float* gamma = (const float*)d_in[1];
  const float* beta  = (const float*)d_in[2];
  const float* wqkv  = (const float*)d_in[3];
  const float* wout  = (const float*)d_in[4];
  const float* bout  = (const float*)d_in[5];
  float* out = (float*)d_out;

  char* ob  = (char*)d_out;
  u16*   xn = (u16*)ob;                               // 64 MB
  float* kv = (float*)(ob + (size_t)M_ * D_ * 2);     // 32 MB

  char* wsb = (char*)d_ws;
  u16*   wqT  = (u16*)  (wsb);                 // 768 KB
  float* pctx = (float*)(wsb + 0x00100000);    // 2 MB
  u16*   FbT  = (u16*)  (wsb + 0x00100000);    // 2 MB (aliases pctx; pctx dead)
  float* psum = (float*)(wsb + 0x00300000);    // 64 KB
  float* ctxT = (float*)(wsb + 0x00310000);    // 128 KB
  u16*   qb   = (u16*)  (wsb + 0x00330000);    // 8 MB

  convw_kernel<<<1536, 256, 0, stream>>>(wqkv, wqT);
  ln_kernel<<<M_/4, 256, 0, stream>>>(x, gamma, beta, xn);
  gemm_qkv<<<dim3(2, M_/128), 256, 0, stream>>>(xn, wqT, qb, kv);
  ctx_partial<<<dim3(16, 4, 8), 256, 0, stream>>>(kv, pctx, psum);
  ctx_reduce<<<32, 1024, 0, stream>>>(pctx, psum, ctxT);
  fold_kernel<<<256, 256, 0, stream>>>(ctxT, wout, FbT);
  gemm_out<<<dim3(D_/128, M_/128), 256, 0, stream>>>(qb, FbT, out, bout, x);
}

// Round 5
// 329.589 us; speedup vs baseline: 1.1485x; 1.0144x over previous
//
#include <hip/hip_runtime.h>

#define B_   8
#define N_   4096
#define D_   1024
#define HID  128
#define QKVW 384
#define M_   (B_*N_)   // 32768 rows

typedef unsigned short u16;
typedef unsigned int   u32;
typedef __attribute__((ext_vector_type(8))) short bf16x8;
typedef __attribute__((ext_vector_type(4))) float f32x4;

__device__ __forceinline__ u16 f2bf(float f){
  u32 u = __float_as_uint(f);
  u32 r = (u + 0x7fffu + ((u >> 16) & 1u)) >> 16;   // RNE
  return (u16)r;
}

// async global->LDS, 16B per lane; LDS dst = wave-uniform base + lane*16
#define GLOAD_LDS16(g, l) __builtin_amdgcn_global_load_lds( \
    (const __attribute__((address_space(1))) unsigned int*)(g), \
    (__attribute__((address_space(3))) unsigned int*)(l), 16, 0, 0)

// ---------------------------------------------------------------------------
// 0. QKV weights -> bf16, k-contiguous transposed
// ---------------------------------------------------------------------------
__global__ void convw_kernel(const float* __restrict__ wqkv, u16* __restrict__ wqT){
  int idx = blockIdx.x * 256 + threadIdx.x;
  if (idx < QKVW * D_){
    int n = idx >> 10, k = idx & 1023;
    wqT[idx] = f2bf(wqkv[(size_t)k * QKVW + n]);
  }
}

// ---------------------------------------------------------------------------
// 1. LayerNorm over dim=1024. Wave-per-row, 4 rows/block, NO barriers.
// ---------------------------------------------------------------------------
__global__ __launch_bounds__(256)
void ln_kernel(const float* __restrict__ x, const float* __restrict__ gamma,
               const float* __restrict__ beta, u16* __restrict__ xn){
  const int wid = threadIdx.x >> 6, lane = threadIdx.x & 63;
  const size_t row = (size_t)blockIdx.x * 4 + wid;
  const float4* xr = (const float4*)(x + row * D_);
  float4 v[4];
  float s = 0.f, q = 0.f;
  #pragma unroll
  for (int j = 0; j < 4; j++){
    v[j] = xr[j*64 + lane];
    s += v[j].x + v[j].y + v[j].z + v[j].w;
    q += v[j].x*v[j].x + v[j].y*v[j].y + v[j].z*v[j].z + v[j].w*v[j].w;
  }
  #pragma unroll
  for (int off = 32; off > 0; off >>= 1){
    s += __shfl_xor(s, off, 64);
    q += __shfl_xor(q, off, 64);
  }
  const float mean = s * (1.f / D_);
  const float rstd = rsqrtf(q * (1.f / D_) - mean * mean + 1e-5f);
  uint2* xo = (uint2*)(xn + row * D_);
  #pragma unroll
  for (int j = 0; j < 4; j++){
    const float4 g  = ((const float4*)gamma)[j*64 + lane];
    const float4 be = ((const float4*)beta)[j*64 + lane];
    float y0 = (v[j].x - mean) * rstd * g.x + be.x;
    float y1 = (v[j].y - mean) * rstd * g.y + be.y;
    float y2 = (v[j].z - mean) * rstd * g.z + be.z;
    float y3 = (v[j].w - mean) * rstd * g.w + be.w;
    uint2 o;
    o.x = (u32)f2bf(y0) | ((u32)f2bf(y1) << 16);
    o.y = (u32)f2bf(y2) | ((u32)f2bf(y3) << 16);
    xo[j*64 + lane] = o;
  }
}

// ---------------------------------------------------------------------------
// 2. QKV GEMM: [M x 384] = xn[M x 1024] * wqT[384 x 1024]^T
//    Tile 128x192, BK=64: LDS 80 KB (2 blocks/CU), half the barriers vs
//    BK=32, 48 MFMA per phase per wave. 2-phase double buffer (R2's proven
//    structure). Row = 8 chunks of 16B; chunk XOR-swizzled by (row&7):
//    stage lane l -> row base+(l>>3), phys chunk l&7, logical (l&7)^(l>>3);
//    read phys = (q+4kk)^(fr&7).
// ---------------------------------------------------------------------------
__device__ __forceinline__ void qkv_compute64(const u16* __restrict__ Asb,
                                              const u16* __restrict__ Bsb,
                                              int wr, int wc, int fr, int q,
                                              f32x4 acc[4][6]){
  #pragma unroll
  for (int kk = 0; kk < 2; kk++){
    const int pc = ((q + 4*kk) ^ (fr & 7)) * 8;
    bf16x8 af[4], bf[6];
    #pragma unroll
    for (int mi = 0; mi < 4; mi++) af[mi] = *(const bf16x8*)&Asb[(wr + mi*16 + fr)*64 + pc];
    #pragma unroll
    for (int ni = 0; ni < 6; ni++) bf[ni] = *(const bf16x8*)&Bsb[(wc + ni*16 + fr)*64 + pc];
    #pragma unroll
    for (int mi = 0; mi < 4; mi++)
      #pragma unroll
      for (int ni = 0; ni < 6; ni++)
        acc[mi][ni] = __builtin_amdgcn_mfma_f32_16x16x32_bf16(af[mi], bf[ni], acc[mi][ni], 0, 0, 0);
  }
}

__global__ __launch_bounds__(256)
void gemm_qkv(const u16* __restrict__ A, const u16* __restrict__ Bt,
              u16* __restrict__ qb, float* __restrict__ kv){
  __shared__ __align__(16) u16 As[2][128 * 64];   // 2 x 16 KB
  __shared__ __align__(16) u16 Bs[2][192 * 64];   // 2 x 24 KB  (80 KB total)
  const int t = threadIdx.x, lane = t & 63, w = t >> 6;
  // XCD-chunked bijective swizzle: 512 wgs = 8 XCDs x 64
  const int lin = blockIdx.x + blockIdx.y * 2;
  const int vid = (lin & 7) * 64 + (lin >> 3);
  const int rowTile = (vid >> 1) * 128;
  const int colTile = (vid & 1) * 192;
  // staging: lane covers row (l>>3), phys chunk l&7, logical (l&7)^(l>>3)
  const int lr8 = lane >> 3;
  const int lc8 = (lane & 7) ^ lr8;
  const u16* pA[4];
  #pragma unroll
  for (int j = 0; j < 4; j++)
    pA[j] = A + (size_t)(rowTile + w*32 + j*8 + lr8) * 1024 + lc8 * 8;
  const u16* pB[6];
  #pragma unroll
  for (int j = 0; j < 6; j++)
    pB[j] = Bt + (size_t)(colTile + w*48 + j*8 + lr8) * 1024 + lc8 * 8;
  const int fr = lane & 15, q = lane >> 4;
  const int wr = (w >> 1) * 64, wc = (w & 1) * 96;

#define QKV_STAGE(bb) do{ \
    _Pragma("unroll") \
    for (int j = 0; j < 4; j++){ GLOAD_LDS16(pA[j], &As[bb][w*2048 + j*512]); pA[j] += 64; } \
    _Pragma("unroll") \
    for (int j = 0; j < 6; j++){ GLOAD_LDS16(pB[j], &Bs[bb][w*3072 + j*512]); pB[j] += 64; } \
  }while(0)

  f32x4 acc[4][6];
  #pragma unroll
  for (int i = 0; i < 4; i++)
    #pragma unroll
    for (int j = 0; j < 6; j++)
      #pragma unroll
      for (int r = 0; r < 4; r++) acc[i][j][r] = 0.f;

  // 16 K-steps of 64. Prologue stages step 0.
  QKV_STAGE(0);
  __syncthreads();
  for (int it = 0; it < 7; ++it){
    QKV_STAGE(1); qkv_compute64(As[0], Bs[0], wr, wc, fr, q, acc); __syncthreads();
    QKV_STAGE(0); qkv_compute64(As[1], Bs[1], wr, wc, fr, q, acc); __syncthreads();
  }
  QKV_STAGE(1); qkv_compute64(As[0], Bs[0], wr, wc, fr, q, acc); __syncthreads();
  qkv_compute64(As[1], Bs[1], wr, wc, fr, q, acc);
#undef QKV_STAGE

  #pragma unroll
  for (int mi = 0; mi < 4; mi++){
    #pragma unroll
    for (int ni = 0; ni < 6; ni++){
      #pragma unroll
      for (int r = 0; r < 4; r++){
        int row = rowTile + wr + mi*16 + q*4 + r;
        int col = colTile + wc + ni*16 + fr;
        float val = acc[mi][ni][r];
        if (col < HID) qb[(size_t)row * HID + col] = f2bf(val);   // q, bf16
        else           kv[(size_t)row * 256 + (col - HID)] = val; // k,v fp32
      }
    }
  }
}

// ---------------------------------------------------------------------------
// 3. Softmax/context partials per (256-row chunk, head, batch). 512 blocks.
// ---------------------------------------------------------------------------
__global__ __launch_bounds__(256)
void ctx_partial(const float* __restrict__ kv, float* __restrict__ pctx,
                 float* __restrict__ psum){
  const int c = blockIdx.x, h = blockIdx.y, b = blockIdx.z;
  const int t = threadIdx.x;
  __shared__ float ek[64][32], vv[64][32];
  const int d = t >> 3, e0 = (t & 7) * 4;
  const int rl = t >> 2, cg = (t & 3) * 8;
  float a0=0.f, a1=0.f, a2=0.f, a3=0.f, ks=0.f;
  const size_t rowbase = (size_t)b * N_ + (size_t)c * 256;
  for (int s = 0; s < 4; ++s){
    __syncthreads();
    const float* src = kv + (rowbase + s*64 + rl) * 256 + h*32 + cg;
    float4 ka = *(const float4*)(src);
    float4 kb = *(const float4*)(src + 4);
    float4 va = *(const float4*)(src + 128);
    float4 vb = *(const float4*)(src + 132);
    float4 ea = make_float4(__expf(ka.x), __expf(ka.y), __expf(ka.z), __expf(ka.w));
    float4 eb = make_float4(__expf(kb.x), __expf(kb.y), __expf(kb.z), __expf(kb.w));
    *(float4*)&ek[rl][cg]     = ea;
    *(float4*)&ek[rl][cg + 4] = eb;
    *(float4*)&vv[rl][cg]     = va;
    *(float4*)&vv[rl][cg + 4] = vb;
    __syncthreads();
    #pragma unroll 8
    for (int n = 0; n < 64; ++n){
      float kd = ek[n][d];
      float4 vn = *(const float4*)&vv[n][e0];
      a0 += kd * vn.x; a1 += kd * vn.y; a2 += kd * vn.z; a3 += kd * vn.w;
      ks += kd;
    }
  }
  float* op = pctx + (((size_t)(b*4 + h) * 16 + c) * 1024) + d*32 + e0;
  *(float4*)op = make_float4(a0, a1, a2, a3);
  if (e0 == 0) psum[((size_t)(b*4 + h) * 16 + c) * 32 + d] = ks;
}

// ---------------------------------------------------------------------------
// 4. Reduce partials -> ctxT[bh][e*32+d] (normalized, q-scale folded)
// ---------------------------------------------------------------------------
__global__ void ctx_reduce(const float* __restrict__ pctx, const float* __restrict__ psum,
                           float* __restrict__ ctxT){
  int bh = blockIdx.x, t = threadIdx.x;   // 1024 threads: t = d*32 + e
  int d = t >> 5, e = t & 31;
  float s = 0.f, S = 0.f;
  for (int c = 0; c < 16; ++c){
    s += pctx[((size_t)bh * 16 + c) * 1024 + t];
    S += psum[((size_t)bh * 16 + c) * 32 + d];
  }
  ctxT[(size_t)bh * 1024 + e*32 + d] = s / S * 0.17677669529663689f; // * 32^-0.5
}

// ---------------------------------------------------------------------------
// 5. Fold context into output weights:
//    FbT[b][c][h*32+d] = sum_e ctxT[b*4+h][e*32+d] * wout[(h*32+e)*1024 + c]
// ---------------------------------------------------------------------------
__global__ __launch_bounds__(256)
void fold_kernel(const float* __restrict__ ctxT, const float* __restrict__ wout,
                 u16* __restrict__ FbT){
  const int b = blockIdx.x >> 5;
  const int c0 = (blockIdx.x & 31) * 32;
  const int t = threadIdx.x;
  __shared__ float cs[4 * 1032];          // +8 pad per head
  #pragma unroll
  for (int i = 0; i < 16; i++){
    int idx = i * 256 + t;                // 0..4095 = h*1024 + (e*32+d)
    cs[(idx >> 10) * 1032 + (idx & 1023)] = ctxT[(size_t)b * 4096 + idx];
  }
  __syncthreads();
  const int c  = c0 + (t & 31);
  const int h  = (t >> 5) & 3;
  const int d0 = (t >> 7) * 16;
  float we[32];
  #pragma unroll
  for (int e = 0; e < 32; e++) we[e] = wout[(size_t)(h*32 + e) * 1024 + c];
  #pragma unroll 4
  for (int d = 0; d < 16; d++){
    float a = 0.f;
    #pragma unroll
    for (int e = 0; e < 32; e++) a += cs[h*1032 + e*32 + (d0 + d)] * we[e];
    FbT[((size_t)b * 1024 + c) * HID + h*32 + d0 + d] = f2bf(a);
  }
}

// ---------------------------------------------------------------------------
// 6. Final GEMM, strip-mined: out[M x 1024] = qb * FbT[b]^T + bias + x.
//    Grid 512: block = (batch, strip of 512 rows, 128-col tile). B (FbT
//    panel, 32 KB) staged ONCE per block; 8 A-subtiles (64 rows) double-
//    buffered; resid prefetched into regs under the MFMAs; batch==XCD so
//    each FbT panel is L2-resident. LDS 64 KB -> 2 blocks/CU.
// ---------------------------------------------------------------------------
__global__ __launch_bounds__(256)
void gemm_out(const u16* __restrict__ A, const u16* __restrict__ Bt,
              float* __restrict__ C, const float* __restrict__ bias,
              const float* __restrict__ resid){
  __shared__ __align__(16) u16 Bs[128 * 128];      // 32 KB, staged once
  __shared__ __align__(16) u16 As[2][64 * 128];    // 2 x 16 KB
  const int t = threadIdx.x, lane = t & 63, w = t >> 6;
  const int lin = blockIdx.x;
  const int batch = lin & 7;             // batch b -> XCD b (round-robin)
  const int idx = lin >> 3;              // 0..63
  const int strip = idx >> 3;            // 0..7
  const int colTile = (idx & 7) * 128;
  const int rowBase = batch * N_ + strip * 512;
  const u16* Bt_b = Bt + (size_t)batch * (1024 * HID);
  const int r4 = lane >> 4;
  const int fr = lane & 15, q = lane >> 4;
  // stage B: 128 cols x 128 k, chunk ^ (row&7) swizzle
  #pragma unroll
  for (int j = 0; j < 8; j++){
    int i = w * 8 + j;
    int lcw = (lane & 15) ^ ((4 * (i & 1)) | r4);
    GLOAD_LDS16(Bt_b + (size_t)(colTile + i*4 + r4) * 128 + lcw * 8, &Bs[i * 512]);
  }
  // stage A subtile 0
  #pragma unroll
  for (int j = 0; j < 4; j++){
    int i = w * 4 + j;
    int lcw = (lane & 15) ^ ((4 * (i & 1)) | r4);
    GLOAD_LDS16(A + (size_t)(rowBase + i*4 + r4) * 128 + lcw * 8, &As[0][i * 512]);
  }
  const int wr = (w >> 1) * 32, wc = (w & 1) * 64;
  float bv[4];
  #pragma unroll
  for (int ni = 0; ni < 4; ni++) bv[ni] = bias[colTile + wc + ni*16 + fr];
  __syncthreads();
  for (int s = 0; s < 8; ++s){
    const u16* Acur = As[s & 1];
    if (s < 7){
      u16* Anxt = (u16*)As[(s + 1) & 1];
      #pragma unroll
      for (int j = 0; j < 4; j++){
        int i = w * 4 + j;
        int lcw = (lane & 15) ^ ((4 * (i & 1)) | r4);
        GLOAD_LDS16(A + (size_t)(rowBase + (s+1)*64 + i*4 + r4) * 128 + lcw * 8,
                    Anxt + i * 512);
      }
    }
    // resid prefetch into regs; latency hides under MFMAs below
    float rbuf[2][4][4];   // [mi][r][ni]
    #pragma unroll
    for (int mi = 0; mi < 2; mi++)
      #pragma unroll
      for (int r = 0; r < 4; r++){
        const float* rp = resid + (size_t)(rowBase + s*64 + wr + mi*16 + q*4 + r) * D_ + colTile;
        #pragma unroll
        for (int ni = 0; ni < 4; ni++)
          rbuf[mi][r][ni] = rp[wc + ni*16 + fr];
      }
    f32x4 acc[2][4];
    #pragma unroll
    for (int mi = 0; mi < 2; mi++)
      #pragma unroll
      for (int ni = 0; ni < 4; ni++)
        #pragma unroll
        for (int r = 0; r < 4; r++) acc[mi][ni][r] = 0.f;
    #pragma unroll
    for (int kk = 0; kk < 4; kk++){
      int pcc = ((kk*4 + q) ^ (fr & 7)) * 8;
      bf16x8 af[2], bf[4];
      #pragma unroll
      for (int mi = 0; mi < 2; mi++) af[mi] = *(const bf16x8*)&Acur[(wr + mi*16 + fr) * 128 + pcc];
      #pragma unroll
      for (int ni = 0; ni < 4; ni++) bf[ni] = *(const bf16x8*)&Bs[(wc + ni*16 + fr) * 128 + pcc];
      #pragma unroll
      for (int mi = 0; mi < 2; mi++)
        #pragma unroll
        for (int ni = 0; ni < 4; ni++)
          acc[mi][ni] = __builtin_amdgcn_mfma_f32_16x16x32_bf16(af[mi], bf[ni], acc[mi][ni], 0, 0, 0);
    }
    __syncthreads();   // drains vmcnt (A_next + rbuf); protects both LDS bufs
    #pragma unroll
    for (int mi = 0; mi < 2; mi++)
      #pragma unroll
      for (int ni = 0; ni < 4; ni++)
        #pragma unroll
        for (int r = 0; r < 4; r++){
          int row = rowBase + s*64 + wr + mi*16 + q*4 + r;
          int col = colTile + wc + ni*16 + fr;
          C[(size_t)row * D_ + col] = acc[mi][ni][r] + bv[ni] + rbuf[mi][r][ni];
        }
  }
}

// ---------------------------------------------------------------------------
// Launch. d_out reuse: [0,64MB)=xn bf16, [64,96MB)=kv fp32 (both dead before
// gemm_out overwrites d_out).
// ws (11.7 MB):
//   wqT @0 (768K) | pctx/FbT @0x100000 (2M, disjoint lifetimes) |
//   psum @0x300000 (64K) | ctxT @0x310000 (128K) | qb @0x330000 (8M)
// ---------------------------------------------------------------------------
extern "C" void kernel_launch(void* const* d_in, const int* in_sizes, int n_in,
                              void* d_out, int out_size, void* d_ws, size_t ws_size,
                              hipStream_t stream){
  const float* x     = (const float*)d_in[0];
  const float* gamma = (const float*)d_in[1];
  const float* beta  = (const float*)d_in[2];
  const float* wqkv  = (const float*)d_in[3];
  const float* wout  = (const float*)d_in[4];
  const float* bout  = (const float*)d_in[5];
  float* out = (float*)d_out;

  char* ob  = (char*)d_out;
  u16*   xn = (u16*)ob;                               // 64 MB
  float* kv = (float*)(ob + (size_t)M_ * D_ * 2);     // 32 MB

  char* wsb = (char*)d_ws;
  u16*   wqT  = (u16*)  (wsb);                 // 768 KB
  float* pctx = (float*)(wsb + 0x00100000);    // 2 MB
  u16*   FbT  = (u16*)  (wsb + 0x00100000);    // 2 MB (aliases pctx; pctx dead)
  float* psum = (float*)(wsb + 0x00300000);    // 64 KB
  float* ctxT = (float*)(wsb + 0x00310000);    // 128 KB
  u16*   qb   = (u16*)  (wsb + 0x00330000);    // 8 MB

  convw_kernel<<<1536, 256, 0, stream>>>(wqkv, wqT);
  ln_kernel<<<M_/4, 256, 0, stream>>>(x, gamma, beta, xn);
  gemm_qkv<<<dim3(2, M_/128), 256, 0, stream>>>(xn, wqT, qb, kv);
  ctx_partial<<<dim3(16, 4, 8), 256, 0, stream>>>(kv, pctx, psum);
  ctx_reduce<<<32, 1024, 0, stream>>>(pctx, psum, ctxT);
  fold_kernel<<<256, 256, 0, stream>>>(ctxT, wout, FbT);
  gemm_out<<<512, 256, 0, stream>>>(qb, FbT, out, bout, x);
}